// Round 4
// baseline (160.601 us; speedup 1.0000x reference)
//
#include <hip/hip_runtime.h>
#include <cstddef>

constexpr int BH = 32;    // batch*heads
constexpr int N  = 8192;  // sequence
constexpr int D  = 64;    // dim
constexpr int BK = 64;    // bucket size
constexpr int NB = 128;   // N / BK buckets
constexpr int NC = 129;   // NB + 1 (padded sk)

// ---------------------------------------------------------------------------
// Kernel A: wave-per-bucket-side, barrier-free, 16 loads in flight per lane.
// grid (NB/4, BH, 2). Wave wv handles bucket j = bx*4+wv of (b, side).
// Lane layout: f = lane&15 (float4 col), r = lane>>4 (strip of 16 rows).
// side 0 (q): qsum + qfirst.  side 1 (k): ksum + kw (suffix-harmonic), W.
// k loads issued row-DESCENDING so the incremental suffix weight consume
// order matches load issue order (progressive vmcnt, full 16-deep MLP).
// ---------------------------------------------------------------------------
__global__ __launch_bounds__(256) void kA(const float* __restrict__ q,
                                          const float* __restrict__ k,
                                          float* __restrict__ qsum,
                                          float* __restrict__ ksum,
                                          float* __restrict__ kw,
                                          float* __restrict__ qfirst,
                                          float* __restrict__ W) {
  const int wv   = threadIdx.x >> 6;
  const int lane = threadIdx.x & 63;
  const int f    = lane & 15;
  const int r    = lane >> 4;                  // strip 0..3 (16 rows each)
  const int j    = blockIdx.x * 4 + wv;
  const int b    = blockIdx.y;
  const int side = blockIdx.z;
  const int base = j * BK;
  const size_t ob = ((size_t)b * NB + j) * D;

  const float* src = (side == 0 ? q : k) + ((size_t)b * N + base) * D;
  const float4* s4 = (const float4*)src;

  if (side == 0) {
    float4 v[16];
#pragma unroll
    for (int p = 0; p < 16; ++p) v[p] = s4[(r * 16 + p) * 16 + f];

    float a[4] = {0, 0, 0, 0};
#pragma unroll
    for (int p = 0; p < 16; ++p) {
      a[0] += v[p].x; a[1] += v[p].y; a[2] += v[p].z; a[3] += v[p].w;
    }
#pragma unroll
    for (int c = 0; c < 4; ++c) {
      a[c] += __shfl_xor(a[c], 16, 64);
      a[c] += __shfl_xor(a[c], 32, 64);
    }
    if (r == 0) {
      ((float4*)(qsum + ob))[f] = make_float4(a[0], a[1], a[2], a[3]);
      ((float4*)(qfirst + ob))[f] = v[0];     // strip 0, p=0 -> bucket row 0
    }
  } else {
    float4 v[16];                              // v[p] = row (r*16 + 15 - p)
#pragma unroll
    for (int p = 0; p < 16; ++p) v[p] = s4[(r * 16 + 15 - p) * 16 + f];

    float ak[4] = {0, 0, 0, 0}, aw[4] = {0, 0, 0, 0};
    float wh = 0.0f;                           // suffix harmonic within strip
#pragma unroll
    for (int p = 0; p < 16; ++p) {
      const int row = r * 16 + 15 - p;
      wh += 1.0f / (float)(base + row + 1);    // include own row (suffix incl.)
      ak[0] += v[p].x; ak[1] += v[p].y; ak[2] += v[p].z; ak[3] += v[p].w;
      aw[0] += v[p].x * wh; aw[1] += v[p].y * wh;
      aw[2] += v[p].z * wh; aw[3] += v[p].w * wh;
    }

    const float w16 = __shfl_xor(wh, 16, 64);
    const float w32 = __shfl_xor(wh, 32, 64);
    const float w48 = __shfl_xor(wh, 48, 64);
    float TU = 0.0f;                           // strips ABOVE r
    if ((r ^ 1) > r) TU += w16;
    if ((r ^ 2) > r) TU += w32;
    if ((r ^ 3) > r) TU += w48;
    const float Wfull = wh + w16 + w32 + w48;

#pragma unroll
    for (int c = 0; c < 4; ++c) aw[c] += TU * ak[c];   // before reduction!
#pragma unroll
    for (int c = 0; c < 4; ++c) {
      ak[c] += __shfl_xor(ak[c], 16, 64); ak[c] += __shfl_xor(ak[c], 32, 64);
      aw[c] += __shfl_xor(aw[c], 16, 64); aw[c] += __shfl_xor(aw[c], 32, 64);
    }
    if (r == 0) {
      ((float4*)(ksum + ob))[f] = make_float4(ak[0], ak[1], ak[2], ak[3]);
      ((float4*)(kw   + ob))[f] = make_float4(aw[0], aw[1], aw[2], aw[3]);
      if (lane == 0 && b == 0) W[j] = Wfull;
    }
  }
}

// ---------------------------------------------------------------------------
// Kernel B: prefix scan. grid (2, BH): x=0 -> q side (sq), x=1 -> k side (skp).
// Stage the scanned array in LDS (coalesced float4), scan from LDS.
// ---------------------------------------------------------------------------
__global__ __launch_bounds__(256) void kB(const float* __restrict__ qsum,
                                          const float* __restrict__ ksum,
                                          const float* __restrict__ kw,
                                          const float* __restrict__ qfirst,
                                          const float* __restrict__ W,
                                          float* __restrict__ sq,
                                          float* __restrict__ skp) {
  const int side = blockIdx.x;
  const int b    = blockIdx.y;
  const int tid  = threadIdx.x;
  const int d    = tid & 63;
  const int jg   = tid >> 6;

  __shared__ float buf[NB * D];
  __shared__ float tot[4 * D];
  __shared__ float Wl[NB];

  const float* src = (side == 0 ? qsum : ksum) + (size_t)b * NB * D;
  {
    const float4* g4 = (const float4*)src;
    float4* l4 = (float4*)buf;
    for (int u = tid; u < NB * D / 4; u += 256) l4[u] = g4[u];
    if (side == 1 && tid < NB) Wl[tid] = W[tid];
  }
  __syncthreads();

  float t0 = 0.0f;
  for (int jj = 0; jj < 32; ++jj) t0 += buf[(jg * 32 + jj) * D + d];
  tot[jg * D + d] = t0;
  __syncthreads();

  float pre = 0.0f;
  for (int g = 0; g < jg; ++g) pre += tot[g * D + d];

  if (side == 0) {
    for (int jj = 0; jj < 32; ++jj) {
      const int j = jg * 32 + jj;
      const size_t o = ((size_t)b * NB + j) * D + d;
      sq[o] = (pre + qfirst[o]) / (float)(j * BK + 1);
      pre += buf[j * D + d];
    }
  } else {
    if (tid < D) skp[(size_t)b * NC * D + tid] = 0.0f;  // pad row 0
    for (int jj = 0; jj < 32; ++jj) {
      const int j = jg * 32 + jj;
      const size_t o = ((size_t)b * NB + j) * D + d;
      skp[((size_t)b * NC + j + 1) * D + d] = pre * Wl[j] + kw[o];
      pre += buf[j * D + d];
    }
  }
}

// ---------------------------------------------------------------------------
// Kernel C: scores+softmax. grid (16, BH): 8-row i-tile per block. Stages only
// the skp rows j <= i_max = T0+7 (XOR-swizzled for conflict-free b128 reads)
// + the 8-row sq tile. Thread (jp, rep): cols {jp, jp+64}, rows {2rep, 2rep+1}.
// Column 128 is always masked -> never computed.
// ---------------------------------------------------------------------------
__global__ __launch_bounds__(256) void kC(const float* __restrict__ sq,
                                          const float* __restrict__ skp,
                                          float* __restrict__ out) {
  const int tile = blockIdx.x, b = blockIdx.y;
  const int tid = threadIdx.x;
  const int jp = tid & 63, rep = tid >> 6;
  const int T0 = tile * 8;
  const int rows = T0 + 8;   // skp rows needed: 0..T0+7

  __shared__ float skpS[NB * D];   // 32 KB max (only `rows` rows staged)
  __shared__ float sqs[8 * D];     // 2 KB

  {
    const float4* g4 = (const float4*)(skp + (size_t)b * NC * D);
    for (int u = tid; u < rows * 16; u += 256) {
      const int row = u >> 4, f = u & 15;
      ((float4*)skpS)[row * 16 + ((f + row) & 15)] = g4[u];
    }
    if (tid < 128)
      ((float4*)sqs)[tid] = ((const float4*)(sq + ((size_t)b * NB + T0) * D))[tid];
  }
  __syncthreads();

  float acc0[2] = {0, 0}, acc1[2] = {0, 0};
  const float4* sk4 = (const float4*)skpS;
  const float4* sq4 = (const float4*)sqs;
#pragma unroll
  for (int d4 = 0; d4 < 16; ++d4) {
    const int slot = (d4 + jp) & 15;           // same slot for jp and jp+64
    const float4 k0 = sk4[jp * 16 + slot];
    const float4 k1 = sk4[(jp + 64) * 16 + slot];  // in-bounds; masked if unstaged
#pragma unroll
    for (int ii = 0; ii < 2; ++ii) {
      const float4 s = sq4[(rep * 2 + ii) * 16 + d4];
      acc0[ii] += s.x * k0.x + s.y * k0.y + s.z * k0.z + s.w * k0.w;
      acc1[ii] += s.x * k1.x + s.y * k1.y + s.z * k1.z + s.w * k1.w;
    }
  }

#pragma unroll
  for (int ii = 0; ii < 2; ++ii) {
    const int i = T0 + rep * 2 + ii;
    const int j0 = jp, j1 = jp + 64;
    const float v0 = acc0[ii] * 0.125f, v1 = acc1[ii] * 0.125f;
    const bool val0 = (j0 <= i), val1 = (j1 <= i);
    float m = fmaxf(val0 ? v0 : -3.402823466e38f, val1 ? v1 : -3.402823466e38f);
#pragma unroll
    for (int s = 1; s < 64; s <<= 1) m = fmaxf(m, __shfl_xor(m, s, 64));
    const float e0 = val0 ? __expf(v0 - m) : 0.0f;
    const float e1 = val1 ? __expf(v1 - m) : 0.0f;
    float ss = e0 + e1;
#pragma unroll
    for (int s = 1; s < 64; s <<= 1) ss += __shfl_xor(ss, s, 64);
    const float rden = 1.0f / ss;
    float* orow = out + ((size_t)b * NB + i) * NC;
    orow[j0] = (j0 < i) ? e0 * rden : 0.0f;
    orow[j1] = (j1 < i) ? e1 * rden : 0.0f;
    if (jp == 0) orow[128] = 0.0f;
  }
}

// ---------------------------------------------------------------------------
extern "C" void kernel_launch(void* const* d_in, const int* in_sizes, int n_in,
                              void* d_out, int out_size, void* d_ws, size_t ws_size,
                              hipStream_t stream) {
  const float* q = (const float*)d_in[0];
  const float* k = (const float*)d_in[1];
  float* out = (float*)d_out;

  float* ws     = (float*)d_ws;
  float* qsum   = ws;                            // BH*NB*D
  float* ksum   = qsum   + (size_t)BH * NB * D;
  float* kw     = ksum   + (size_t)BH * NB * D;
  float* qfirst = kw     + (size_t)BH * NB * D;
  float* sq     = qfirst + (size_t)BH * NB * D;
  float* skp    = sq     + (size_t)BH * NB * D;  // BH*NC*D
  float* W      = skp    + (size_t)BH * NC * D;  // NB

  kA<<<dim3(NB / 4, BH, 2), 256, 0, stream>>>(q, k, qsum, ksum, kw, qfirst, W);
  kB<<<dim3(2, BH), 256, 0, stream>>>(qsum, ksum, kw, qfirst, W, sq, skp);
  kC<<<dim3(16, BH), 256, 0, stream>>>(sq, skp, out);
}

// Round 5
// 156.685 us; speedup vs baseline: 1.0250x; 1.0250x over previous
//
#include <hip/hip_runtime.h>
#include <cstddef>

constexpr int BH = 32;    // batch*heads
constexpr int N  = 8192;  // sequence
constexpr int D  = 64;    // dim
constexpr int BK = 64;    // bucket size
constexpr int NB = 128;   // N / BK buckets
constexpr int NC = 129;   // NB + 1 (padded sk)

// ---------------------------------------------------------------------------
// Kernel A: block per (bucket j, b). Loads BOTH the q-bucket and k-bucket:
// 8 independent float4 loads per thread, all issued before any consume.
// __launch_bounds__(256, 1) gives the register allocator headroom to keep
// them live (R4 lesson: default bounds clamp VGPR to 32 -> 4-deep MLP).
// Each wave-load instruction covers a contiguous 1 KB segment (lanes 0..63
// cover 4 consecutive rows). tailw via in-wave suffix scan; 1 barrier.
// ---------------------------------------------------------------------------
__global__ __launch_bounds__(256, 1) void kA(const float* __restrict__ q,
                                             const float* __restrict__ k,
                                             float* __restrict__ qsum,
                                             float* __restrict__ ksum,
                                             float* __restrict__ kw,
                                             float* __restrict__ qfirst,
                                             float* __restrict__ W) {
  const int j = blockIdx.x, b = blockIdx.y;
  const int tid  = threadIdx.x;
  const int f    = tid & 15;      // float4 column
  const int rr   = tid >> 4;      // row-group 0..15 (rows rr + 16p)
  const int w    = tid >> 6;      // wave
  const int lane = tid & 63;
  const int base = j * BK;
  const size_t ob = ((size_t)b * NB + j) * D;

  const float4* q4 = (const float4*)(q + ((size_t)b * N + base) * D);
  const float4* k4 = (const float4*)(k + ((size_t)b * N + base) * D);

  // ---- 8 independent loads, issued before any consumer
  float4 vq[4], vk[4];
#pragma unroll
  for (int p = 0; p < 4; ++p) vq[p] = q4[(16 * p + rr) * 16 + f];
#pragma unroll
  for (int p = 0; p < 4; ++p) vk[p] = k4[(16 * p + rr) * 16 + f];

  // ---- in-wave suffix harmonic scan: scan[t] = sum_{u>=t} 1/(base+u+1)
  float x = 1.0f / (float)(base + lane + 1);
#pragma unroll
  for (int s = 1; s < 64; s <<= 1) {
    const float y = __shfl_down(x, s, 64);
    if (lane + s < 64) x += y;
  }
  // tailw for this thread's 4 rows
  float tw[4];
#pragma unroll
  for (int p = 0; p < 4; ++p) tw[p] = __shfl(x, 16 * p + rr, 64);

  // ---- accumulate
  float aq[4] = {0, 0, 0, 0}, ak[4] = {0, 0, 0, 0}, aw[4] = {0, 0, 0, 0};
#pragma unroll
  for (int p = 0; p < 4; ++p) {
    aq[0] += vq[p].x; aq[1] += vq[p].y; aq[2] += vq[p].z; aq[3] += vq[p].w;
    ak[0] += vk[p].x; ak[1] += vk[p].y; ak[2] += vk[p].z; ak[3] += vk[p].w;
    aw[0] += vk[p].x * tw[p]; aw[1] += vk[p].y * tw[p];
    aw[2] += vk[p].z * tw[p]; aw[3] += vk[p].w * tw[p];
  }

  // ---- reduce over rr&3 inside the wave (lane = (rr&3)*16 + f)
#pragma unroll
  for (int c = 0; c < 4; ++c) {
    aq[c] += __shfl_xor(aq[c], 16, 64); aq[c] += __shfl_xor(aq[c], 32, 64);
    ak[c] += __shfl_xor(ak[c], 16, 64); ak[c] += __shfl_xor(ak[c], 32, 64);
    aw[c] += __shfl_xor(aw[c], 16, 64); aw[c] += __shfl_xor(aw[c], 32, 64);
  }

  __shared__ float red[3][4][D];   // 3 KB
  if (lane < 16) {                 // lane == f
    ((float4*)&red[0][w][0])[f] = make_float4(aq[0], aq[1], aq[2], aq[3]);
    ((float4*)&red[1][w][0])[f] = make_float4(ak[0], ak[1], ak[2], ak[3]);
    ((float4*)&red[2][w][0])[f] = make_float4(aw[0], aw[1], aw[2], aw[3]);
  }
  if (rr == 0) {                   // rows 16p+0, p=0 -> bucket row 0
    ((float4*)(qfirst + ob))[f] = vq[0];
  }
  if (tid == 0 && b == 0) W[j] = x;  // lane 0: full-bucket harmonic
  __syncthreads();

  if (tid < 192) {
    const int arr = tid >> 6, d = tid & 63;
    const float s = red[arr][0][d] + red[arr][1][d] + red[arr][2][d] + red[arr][3][d];
    float* dst = (arr == 0) ? qsum : (arr == 1) ? ksum : kw;
    dst[ob + d] = s;
  }
}

// ---------------------------------------------------------------------------
// Kernel B: prefix scan. grid (2, BH): x=0 -> q side (sq), x=1 -> k side (skp).
// Stage the scanned array in LDS (coalesced float4), scan from LDS.
// ---------------------------------------------------------------------------
__global__ __launch_bounds__(256) void kB(const float* __restrict__ qsum,
                                          const float* __restrict__ ksum,
                                          const float* __restrict__ kw,
                                          const float* __restrict__ qfirst,
                                          const float* __restrict__ W,
                                          float* __restrict__ sq,
                                          float* __restrict__ skp) {
  const int side = blockIdx.x;
  const int b    = blockIdx.y;
  const int tid  = threadIdx.x;
  const int d    = tid & 63;
  const int jg   = tid >> 6;

  __shared__ float buf[NB * D];
  __shared__ float tot[4 * D];
  __shared__ float Wl[NB];

  const float* src = (side == 0 ? qsum : ksum) + (size_t)b * NB * D;
  {
    const float4* g4 = (const float4*)src;
    float4* l4 = (float4*)buf;
    for (int u = tid; u < NB * D / 4; u += 256) l4[u] = g4[u];
    if (side == 1 && tid < NB) Wl[tid] = W[tid];
  }
  __syncthreads();

  float t0 = 0.0f;
  for (int jj = 0; jj < 32; ++jj) t0 += buf[(jg * 32 + jj) * D + d];
  tot[jg * D + d] = t0;
  __syncthreads();

  float pre = 0.0f;
  for (int g = 0; g < jg; ++g) pre += tot[g * D + d];

  if (side == 0) {
    for (int jj = 0; jj < 32; ++jj) {
      const int j = jg * 32 + jj;
      const size_t o = ((size_t)b * NB + j) * D + d;
      sq[o] = (pre + qfirst[o]) / (float)(j * BK + 1);
      pre += buf[j * D + d];
    }
  } else {
    if (tid < D) skp[(size_t)b * NC * D + tid] = 0.0f;  // pad row 0
    for (int jj = 0; jj < 32; ++jj) {
      const int j = jg * 32 + jj;
      const size_t o = ((size_t)b * NB + j) * D + d;
      skp[((size_t)b * NC + j + 1) * D + d] = pre * Wl[j] + kw[o];
      pre += buf[j * D + d];
    }
  }
}

// ---------------------------------------------------------------------------
// Kernel C: scores+softmax. grid (16, BH): 8-row i-tile per block. Stages only
// the skp rows j <= i_max = T0+7 (XOR-swizzled for conflict-free b128 reads)
// + the 8-row sq tile. Thread (jp, rep): cols {jp, jp+64}, rows {2rep, 2rep+1}.
// Column 128 is always masked -> never computed.
// ---------------------------------------------------------------------------
__global__ __launch_bounds__(256) void kC(const float* __restrict__ sq,
                                          const float* __restrict__ skp,
                                          float* __restrict__ out) {
  const int tile = blockIdx.x, b = blockIdx.y;
  const int tid = threadIdx.x;
  const int jp = tid & 63, rep = tid >> 6;
  const int T0 = tile * 8;
  const int rows = T0 + 8;   // skp rows needed: 0..T0+7

  __shared__ float skpS[NB * D];   // 32 KB max (only `rows` rows staged)
  __shared__ float sqs[8 * D];     // 2 KB

  {
    const float4* g4 = (const float4*)(skp + (size_t)b * NC * D);
    for (int u = tid; u < rows * 16; u += 256) {
      const int row = u >> 4, f = u & 15;
      ((float4*)skpS)[row * 16 + ((f + row) & 15)] = g4[u];
    }
    if (tid < 128)
      ((float4*)sqs)[tid] = ((const float4*)(sq + ((size_t)b * NB + T0) * D))[tid];
  }
  __syncthreads();

  float acc0[2] = {0, 0}, acc1[2] = {0, 0};
  const float4* sk4 = (const float4*)skpS;
  const float4* sq4 = (const float4*)sqs;
#pragma unroll
  for (int d4 = 0; d4 < 16; ++d4) {
    const int slot = (d4 + jp) & 15;           // same slot for jp and jp+64
    const float4 k0 = sk4[jp * 16 + slot];
    const float4 k1 = sk4[(jp + 64) * 16 + slot];  // in-bounds; masked if unstaged
#pragma unroll
    for (int ii = 0; ii < 2; ++ii) {
      const float4 s = sq4[(rep * 2 + ii) * 16 + d4];
      acc0[ii] += s.x * k0.x + s.y * k0.y + s.z * k0.z + s.w * k0.w;
      acc1[ii] += s.x * k1.x + s.y * k1.y + s.z * k1.z + s.w * k1.w;
    }
  }

#pragma unroll
  for (int ii = 0; ii < 2; ++ii) {
    const int i = T0 + rep * 2 + ii;
    const int j0 = jp, j1 = jp + 64;
    const float v0 = acc0[ii] * 0.125f, v1 = acc1[ii] * 0.125f;
    const bool val0 = (j0 <= i), val1 = (j1 <= i);
    float m = fmaxf(val0 ? v0 : -3.402823466e38f, val1 ? v1 : -3.402823466e38f);
#pragma unroll
    for (int s = 1; s < 64; s <<= 1) m = fmaxf(m, __shfl_xor(m, s, 64));
    const float e0 = val0 ? __expf(v0 - m) : 0.0f;
    const float e1 = val1 ? __expf(v1 - m) : 0.0f;
    float ss = e0 + e1;
#pragma unroll
    for (int s = 1; s < 64; s <<= 1) ss += __shfl_xor(ss, s, 64);
    const float rden = 1.0f / ss;
    float* orow = out + ((size_t)b * NB + i) * NC;
    orow[j0] = (j0 < i) ? e0 * rden : 0.0f;
    orow[j1] = (j1 < i) ? e1 * rden : 0.0f;
    if (jp == 0) orow[128] = 0.0f;
  }
}

// ---------------------------------------------------------------------------
extern "C" void kernel_launch(void* const* d_in, const int* in_sizes, int n_in,
                              void* d_out, int out_size, void* d_ws, size_t ws_size,
                              hipStream_t stream) {
  const float* q = (const float*)d_in[0];
  const float* k = (const float*)d_in[1];
  float* out = (float*)d_out;

  float* ws     = (float*)d_ws;
  float* qsum   = ws;                            // BH*NB*D
  float* ksum   = qsum   + (size_t)BH * NB * D;
  float* kw     = ksum   + (size_t)BH * NB * D;
  float* qfirst = kw     + (size_t)BH * NB * D;
  float* sq     = qfirst + (size_t)BH * NB * D;
  float* skp    = sq     + (size_t)BH * NB * D;  // BH*NC*D
  float* W      = skp    + (size_t)BH * NC * D;  // NB

  kA<<<dim3(NB, BH), 256, 0, stream>>>(q, k, qsum, ksum, kw, qfirst, W);
  kB<<<dim3(2, BH), 256, 0, stream>>>(qsum, ksum, kw, qfirst, W, sq, skp);
  kC<<<dim3(16, BH), 256, 0, stream>>>(sq, skp, out);
}

// Round 6
// 155.937 us; speedup vs baseline: 1.0299x; 1.0048x over previous
//
#include <hip/hip_runtime.h>
#include <cstddef>
#include <cstdint>

constexpr int BH = 32;    // batch*heads
constexpr int N  = 8192;  // sequence
constexpr int D  = 64;    // dim
constexpr int BK = 64;    // bucket size
constexpr int NB = 128;   // N / BK buckets
constexpr int NC = 129;   // NB + 1 (padded sk)

#define GLOBAL_AS(p) ((const __attribute__((address_space(1))) uint32_t*)(p))
#define LDS_AS(p)    ((__attribute__((address_space(3))) uint32_t*)(p))

// ---------------------------------------------------------------------------
// Kernel A: block per (bucket j, b). Stages q-bucket (16 KB) + k-bucket
// (16 KB) into LDS via global_load_lds DMA (no VGPR destination -> the
// register allocator CANNOT collapse the pipeline; requests live in the
// vmcnt queue). 8 DMA ops per wave issued back-to-back, one barrier, then
// reduce from LDS (b128 reads, 2-way bank aliasing = free).
// ---------------------------------------------------------------------------
__global__ __launch_bounds__(256) void kA(const float* __restrict__ q,
                                          const float* __restrict__ k,
                                          float* __restrict__ qsum,
                                          float* __restrict__ ksum,
                                          float* __restrict__ kw,
                                          float* __restrict__ qfirst,
                                          float* __restrict__ W) {
  const int j = blockIdx.x, b = blockIdx.y;
  const int tid  = threadIdx.x;
  const int f    = tid & 15;      // float4 column
  const int rr   = tid >> 4;      // row-group 0..15 (rows 16p + rr)
  const int w    = tid >> 6;      // wave
  const int lane = tid & 63;
  const int base = j * BK;
  const size_t ob = ((size_t)b * NB + j) * D;

  __shared__ float4 buf4[2048];    // 32 KB: [0,1024) q-bucket, [1024,2048) k
  __shared__ float red[3][4][D];   // 3 KB

  const float4* q4 = (const float4*)(q + ((size_t)b * N + base) * D);
  const float4* k4 = (const float4*)(k + ((size_t)b * N + base) * D);

  // ---- async DMA staging: 8 ops/wave, each moves 64 lanes x 16 B = 1 KB
#pragma unroll
  for (int p = 0; p < 4; ++p) {
    const int u = w * 256 + p * 64 + lane;   // 0..1023 per side, lane-contig
    __builtin_amdgcn_global_load_lds(GLOBAL_AS(q4 + u), LDS_AS(buf4 + u), 16, 0, 0);
    __builtin_amdgcn_global_load_lds(GLOBAL_AS(k4 + u), LDS_AS(buf4 + 1024 + u), 16, 0, 0);
  }

  // ---- in-wave suffix harmonic scan (overlaps the DMA):
  // x[lane] = sum_{u>=lane} 1/(base+u+1)
  float x = 1.0f / (float)(base + lane + 1);
#pragma unroll
  for (int s = 1; s < 64; s <<= 1) {
    const float y = __shfl_down(x, s, 64);
    if (lane + s < 64) x += y;
  }
  float tw[4];
#pragma unroll
  for (int p = 0; p < 4; ++p) tw[p] = __shfl(x, 16 * p + rr, 64);

  __syncthreads();   // drains vmcnt(0): all DMA landed in LDS

  // ---- accumulate from LDS
  float aq[4] = {0, 0, 0, 0}, ak[4] = {0, 0, 0, 0}, aw[4] = {0, 0, 0, 0};
#pragma unroll
  for (int p = 0; p < 4; ++p) {
    const float4 vq = buf4[(16 * p + rr) * 16 + f];
    const float4 vk = buf4[1024 + (16 * p + rr) * 16 + f];
    aq[0] += vq.x; aq[1] += vq.y; aq[2] += vq.z; aq[3] += vq.w;
    ak[0] += vk.x; ak[1] += vk.y; ak[2] += vk.z; ak[3] += vk.w;
    aw[0] += vk.x * tw[p]; aw[1] += vk.y * tw[p];
    aw[2] += vk.z * tw[p]; aw[3] += vk.w * tw[p];
  }

  // ---- reduce over the 4 row-groups resident in this wave
#pragma unroll
  for (int c = 0; c < 4; ++c) {
    aq[c] += __shfl_xor(aq[c], 16, 64); aq[c] += __shfl_xor(aq[c], 32, 64);
    ak[c] += __shfl_xor(ak[c], 16, 64); ak[c] += __shfl_xor(ak[c], 32, 64);
    aw[c] += __shfl_xor(aw[c], 16, 64); aw[c] += __shfl_xor(aw[c], 32, 64);
  }
  if (lane < 16) {                 // lane == f
    ((float4*)&red[0][w][0])[f] = make_float4(aq[0], aq[1], aq[2], aq[3]);
    ((float4*)&red[1][w][0])[f] = make_float4(ak[0], ak[1], ak[2], ak[3]);
    ((float4*)&red[2][w][0])[f] = make_float4(aw[0], aw[1], aw[2], aw[3]);
  }
  if (tid < 16) {                  // bucket row 0 (q) -> qfirst
    ((float4*)(qfirst + ob))[tid] = buf4[tid];
  }
  if (tid == 0 && b == 0) W[j] = x;   // lane 0: full-bucket harmonic
  __syncthreads();

  if (tid < 192) {
    const int arr = tid >> 6, d = tid & 63;
    const float s = red[arr][0][d] + red[arr][1][d] + red[arr][2][d] + red[arr][3][d];
    float* dst = (arr == 0) ? qsum : (arr == 1) ? ksum : kw;
    dst[ob + d] = s;
  }
}

// ---------------------------------------------------------------------------
// Kernel B: prefix scan. grid (2, BH): x=0 -> q side (sq), x=1 -> k side (skp).
// ---------------------------------------------------------------------------
__global__ __launch_bounds__(256) void kB(const float* __restrict__ qsum,
                                          const float* __restrict__ ksum,
                                          const float* __restrict__ kw,
                                          const float* __restrict__ qfirst,
                                          const float* __restrict__ W,
                                          float* __restrict__ sq,
                                          float* __restrict__ skp) {
  const int side = blockIdx.x;
  const int b    = blockIdx.y;
  const int tid  = threadIdx.x;
  const int d    = tid & 63;
  const int jg   = tid >> 6;

  __shared__ float buf[NB * D];
  __shared__ float tot[4 * D];
  __shared__ float Wl[NB];

  const float* src = (side == 0 ? qsum : ksum) + (size_t)b * NB * D;
  {
    const float4* g4 = (const float4*)src;
    float4* l4 = (float4*)buf;
    for (int u = tid; u < NB * D / 4; u += 256) l4[u] = g4[u];
    if (side == 1 && tid < NB) Wl[tid] = W[tid];
  }
  __syncthreads();

  float t0 = 0.0f;
  for (int jj = 0; jj < 32; ++jj) t0 += buf[(jg * 32 + jj) * D + d];
  tot[jg * D + d] = t0;
  __syncthreads();

  float pre = 0.0f;
  for (int g = 0; g < jg; ++g) pre += tot[g * D + d];

  if (side == 0) {
    for (int jj = 0; jj < 32; ++jj) {
      const int j = jg * 32 + jj;
      const size_t o = ((size_t)b * NB + j) * D + d;
      sq[o] = (pre + qfirst[o]) / (float)(j * BK + 1);
      pre += buf[j * D + d];
    }
  } else {
    if (tid < D) skp[(size_t)b * NC * D + tid] = 0.0f;  // pad row 0
    for (int jj = 0; jj < 32; ++jj) {
      const int j = jg * 32 + jj;
      const size_t o = ((size_t)b * NB + j) * D + d;
      skp[((size_t)b * NC + j + 1) * D + d] = pre * Wl[j] + kw[o];
      pre += buf[j * D + d];
    }
  }
}

// ---------------------------------------------------------------------------
// Kernel C: scores+softmax. grid (16, BH): 8-row i-tile per block. Stages only
// the skp rows j <= i_max = T0+7 (XOR-swizzled) + the 8-row sq tile.
// Thread (jp, rep): cols {jp, jp+64}, rows {2rep, 2rep+1}. Col 128 never computed.
// ---------------------------------------------------------------------------
__global__ __launch_bounds__(256) void kC(const float* __restrict__ sq,
                                          const float* __restrict__ skp,
                                          float* __restrict__ out) {
  const int tile = blockIdx.x, b = blockIdx.y;
  const int tid = threadIdx.x;
  const int jp = tid & 63, rep = tid >> 6;
  const int T0 = tile * 8;
  const int rows = T0 + 8;   // skp rows needed: 0..T0+7

  __shared__ float skpS[NB * D];   // 32 KB max (only `rows` rows staged)
  __shared__ float sqs[8 * D];     // 2 KB

  {
    const float4* g4 = (const float4*)(skp + (size_t)b * NC * D);
    for (int u = tid; u < rows * 16; u += 256) {
      const int row = u >> 4, f = u & 15;
      ((float4*)skpS)[row * 16 + ((f + row) & 15)] = g4[u];
    }
    if (tid < 128)
      ((float4*)sqs)[tid] = ((const float4*)(sq + ((size_t)b * NB + T0) * D))[tid];
  }
  __syncthreads();

  float acc0[2] = {0, 0}, acc1[2] = {0, 0};
  const float4* sk4 = (const float4*)skpS;
  const float4* sq4 = (const float4*)sqs;
#pragma unroll
  for (int d4 = 0; d4 < 16; ++d4) {
    const int slot = (d4 + jp) & 15;           // same slot for jp and jp+64
    const float4 k0 = sk4[jp * 16 + slot];
    const float4 k1 = sk4[(jp + 64) * 16 + slot];
#pragma unroll
    for (int ii = 0; ii < 2; ++ii) {
      const float4 s = sq4[(rep * 2 + ii) * 16 + d4];
      acc0[ii] += s.x * k0.x + s.y * k0.y + s.z * k0.z + s.w * k0.w;
      acc1[ii] += s.x * k1.x + s.y * k1.y + s.z * k1.z + s.w * k1.w;
    }
  }

#pragma unroll
  for (int ii = 0; ii < 2; ++ii) {
    const int i = T0 + rep * 2 + ii;
    const int j0 = jp, j1 = jp + 64;
    const float v0 = acc0[ii] * 0.125f, v1 = acc1[ii] * 0.125f;
    const bool val0 = (j0 <= i), val1 = (j1 <= i);
    float m = fmaxf(val0 ? v0 : -3.402823466e38f, val1 ? v1 : -3.402823466e38f);
#pragma unroll
    for (int s = 1; s < 64; s <<= 1) m = fmaxf(m, __shfl_xor(m, s, 64));
    const float e0 = val0 ? __expf(v0 - m) : 0.0f;
    const float e1 = val1 ? __expf(v1 - m) : 0.0f;
    float ss = e0 + e1;
#pragma unroll
    for (int s = 1; s < 64; s <<= 1) ss += __shfl_xor(ss, s, 64);
    const float rden = 1.0f / ss;
    float* orow = out + ((size_t)b * NB + i) * NC;
    orow[j0] = (j0 < i) ? e0 * rden : 0.0f;
    orow[j1] = (j1 < i) ? e1 * rden : 0.0f;
    if (jp == 0) orow[128] = 0.0f;
  }
}

// ---------------------------------------------------------------------------
extern "C" void kernel_launch(void* const* d_in, const int* in_sizes, int n_in,
                              void* d_out, int out_size, void* d_ws, size_t ws_size,
                              hipStream_t stream) {
  const float* q = (const float*)d_in[0];
  const float* k = (const float*)d_in[1];
  float* out = (float*)d_out;

  float* ws     = (float*)d_ws;
  float* qsum   = ws;                            // BH*NB*D
  float* ksum   = qsum   + (size_t)BH * NB * D;
  float* kw     = ksum   + (size_t)BH * NB * D;
  float* qfirst = kw     + (size_t)BH * NB * D;
  float* sq     = qfirst + (size_t)BH * NB * D;
  float* skp    = sq     + (size_t)BH * NB * D;  // BH*NC*D
  float* W      = skp    + (size_t)BH * NC * D;  // NB

  kA<<<dim3(NB, BH), 256, 0, stream>>>(q, k, qsum, ksum, kw, qfirst, W);
  kB<<<dim3(2, BH), 256, 0, stream>>>(qsum, ksum, kw, qfirst, W, sq, skp);
  kC<<<dim3(16, BH), 256, 0, stream>>>(sq, skp, out);
}

// Round 8
// 149.720 us; speedup vs baseline: 1.0727x; 1.0415x over previous
//
#include <hip/hip_runtime.h>
#include <cstddef>

constexpr int BH = 32;    // batch*heads
constexpr int N  = 8192;  // sequence
constexpr int D  = 64;    // dim
constexpr int BK = 64;    // bucket size
constexpr int NB = 128;   // N / BK buckets
constexpr int NC = 129;   // NB + 1 (padded sk)

typedef float v4f __attribute__((ext_vector_type(4)));  // native vector for NT builtins

// ---------------------------------------------------------------------------
// Kernel A: one block per (bucket j, b, side) — R3 structure (best measured:
// 42.2 us) with NON-TEMPORAL loads (single-variable change): bypass cache
// allocation on the 128 MiB streaming read to test whether the ~3.1 TB/s
// read cap is an allocation-path artifact.
// side 0: q -> qsum + qfirst.  side 1: k -> ksum + kw + W.
// ---------------------------------------------------------------------------
__global__ __launch_bounds__(256) void kA(const float* __restrict__ q,
                                          const float* __restrict__ k,
                                          float* __restrict__ qsum,
                                          float* __restrict__ ksum,
                                          float* __restrict__ kw,
                                          float* __restrict__ qfirst,
                                          float* __restrict__ W) {
  const int j = blockIdx.x, b = blockIdx.y, side = blockIdx.z;
  const int tid = threadIdx.x;
  const int f = tid & 15, r = tid >> 4, w = tid >> 6, lane = tid & 63;
  const int base = j * BK;

  __shared__ float tailw[BK];
  __shared__ float red[2][4][D];

  const float* src = (side == 0 ? q : k) + ((size_t)b * N + base) * D;
  const v4f* s4 = (const v4f*)src;

  // 4 independent non-temporal loads, issued before any barrier
  v4f v[4];
#pragma unroll
  for (int p = 0; p < 4; ++p) v[p] = __builtin_nontemporal_load(&s4[(r + 16 * p) * 16 + f]);

  if (side == 1) {
    if (w == 0) {
      float x = 1.0f / (float)(base + lane + 1);
#pragma unroll
      for (int s = 1; s < 64; s <<= 1) {
        float y = __shfl_down(x, s, 64);
        if (lane + s < 64) x += y;
      }
      tailw[lane] = x;                       // suffix harmonic within bucket
      if (lane == 0 && b == 0) W[j] = x;     // full-bucket harmonic
    }
    __syncthreads();
  }

  float a0[4] = {0, 0, 0, 0}, a1[4] = {0, 0, 0, 0};
  if (side == 0) {
#pragma unroll
    for (int p = 0; p < 4; ++p) {
      a0[0] += v[p].x; a0[1] += v[p].y; a0[2] += v[p].z; a0[3] += v[p].w;
    }
  } else {
#pragma unroll
    for (int p = 0; p < 4; ++p) {
      const float tw = tailw[r + 16 * p];
      a0[0] += v[p].x; a0[1] += v[p].y; a0[2] += v[p].z; a0[3] += v[p].w;
      a1[0] += v[p].x * tw; a1[1] += v[p].y * tw;
      a1[2] += v[p].z * tw; a1[3] += v[p].w * tw;
    }
  }

  // in-wave reduce over the 4 row-groups resident in this wave
#pragma unroll
  for (int c = 0; c < 4; ++c) {
    a0[c] += __shfl_xor(a0[c], 16, 64); a0[c] += __shfl_xor(a0[c], 32, 64);
    a1[c] += __shfl_xor(a1[c], 16, 64); a1[c] += __shfl_xor(a1[c], 32, 64);
  }
  if (lane < 16) {  // lane == f
    ((float4*)&red[0][w][0])[f] = make_float4(a0[0], a0[1], a0[2], a0[3]);
    ((float4*)&red[1][w][0])[f] = make_float4(a1[0], a1[1], a1[2], a1[3]);
  }
  __syncthreads();

  const size_t ob = ((size_t)b * NB + j) * D;
  if (tid < D) {
    const float s0 = red[0][0][tid] + red[0][1][tid] + red[0][2][tid] + red[0][3][tid];
    if (side == 0) {
      qsum[ob + tid] = s0;
    } else {
      ksum[ob + tid] = s0;
      kw[ob + tid] = red[1][0][tid] + red[1][1][tid] + red[1][2][tid] + red[1][3][tid];
    }
  }
  if (side == 0 && r == 0) {  // this thread's first load is bucket row 0
    v4f qf = v[0];
    ((float4*)(qfirst + ob))[f] = make_float4(qf.x, qf.y, qf.z, qf.w);
  }
}

// ---------------------------------------------------------------------------
// Kernel B: prefix scan. grid (2, BH): x=0 -> q side (sq), x=1 -> k side (skp).
// Stage the scanned array in LDS (coalesced float4), scan from LDS.
// ---------------------------------------------------------------------------
__global__ __launch_bounds__(256) void kB(const float* __restrict__ qsum,
                                          const float* __restrict__ ksum,
                                          const float* __restrict__ kw,
                                          const float* __restrict__ qfirst,
                                          const float* __restrict__ W,
                                          float* __restrict__ sq,
                                          float* __restrict__ skp) {
  const int side = blockIdx.x;
  const int b    = blockIdx.y;
  const int tid  = threadIdx.x;
  const int d    = tid & 63;
  const int jg   = tid >> 6;

  __shared__ float buf[NB * D];
  __shared__ float tot[4 * D];
  __shared__ float Wl[NB];

  const float* src = (side == 0 ? qsum : ksum) + (size_t)b * NB * D;
  {
    const float4* g4 = (const float4*)src;
    float4* l4 = (float4*)buf;
    for (int u = tid; u < NB * D / 4; u += 256) l4[u] = g4[u];
    if (side == 1 && tid < NB) Wl[tid] = W[tid];
  }
  __syncthreads();

  float t0 = 0.0f;
  for (int jj = 0; jj < 32; ++jj) t0 += buf[(jg * 32 + jj) * D + d];
  tot[jg * D + d] = t0;
  __syncthreads();

  float pre = 0.0f;
  for (int g = 0; g < jg; ++g) pre += tot[g * D + d];

  if (side == 0) {
    for (int jj = 0; jj < 32; ++jj) {
      const int j = jg * 32 + jj;
      const size_t o = ((size_t)b * NB + j) * D + d;
      sq[o] = (pre + qfirst[o]) / (float)(j * BK + 1);
      pre += buf[j * D + d];
    }
  } else {
    if (tid < D) skp[(size_t)b * NC * D + tid] = 0.0f;  // pad row 0
    for (int jj = 0; jj < 32; ++jj) {
      const int j = jg * 32 + jj;
      const size_t o = ((size_t)b * NB + j) * D + d;
      skp[((size_t)b * NC + j + 1) * D + d] = pre * Wl[j] + kw[o];
      pre += buf[j * D + d];
    }
  }
}

// ---------------------------------------------------------------------------
// Kernel C: scores+softmax. grid (16, BH): 8-row i-tile per block. Stages only
// the skp rows j <= i_max = T0+7 (XOR-swizzled) + the 8-row sq tile.
// Thread (jp, rep): cols {jp, jp+64}, rows {2rep, 2rep+1}. Col 128 never computed.
// ---------------------------------------------------------------------------
__global__ __launch_bounds__(256) void kC(const float* __restrict__ sq,
                                          const float* __restrict__ skp,
                                          float* __restrict__ out) {
  const int tile = blockIdx.x, b = blockIdx.y;
  const int tid = threadIdx.x;
  const int jp = tid & 63, rep = tid >> 6;
  const int T0 = tile * 8;
  const int rows = T0 + 8;   // skp rows needed: 0..T0+7

  __shared__ float skpS[NB * D];   // 32 KB max (only `rows` rows staged)
  __shared__ float sqs[8 * D];     // 2 KB

  {
    const float4* g4 = (const float4*)(skp + (size_t)b * NC * D);
    for (int u = tid; u < rows * 16; u += 256) {
      const int row = u >> 4, f = u & 15;
      ((float4*)skpS)[row * 16 + ((f + row) & 15)] = g4[u];
    }
    if (tid < 128)
      ((float4*)sqs)[tid] = ((const float4*)(sq + ((size_t)b * NB + T0) * D))[tid];
  }
  __syncthreads();

  float acc0[2] = {0, 0}, acc1[2] = {0, 0};
  const float4* sk4 = (const float4*)skpS;
  const float4* sq4 = (const float4*)sqs;
#pragma unroll
  for (int d4 = 0; d4 < 16; ++d4) {
    const int slot = (d4 + jp) & 15;           // same slot for jp and jp+64
    const float4 k0 = sk4[jp * 16 + slot];
    const float4 k1 = sk4[(jp + 64) * 16 + slot];
#pragma unroll
    for (int ii = 0; ii < 2; ++ii) {
      const float4 s = sq4[(rep * 2 + ii) * 16 + d4];
      acc0[ii] += s.x * k0.x + s.y * k0.y + s.z * k0.z + s.w * k0.w;
      acc1[ii] += s.x * k1.x + s.y * k1.y + s.z * k1.z + s.w * k1.w;
    }
  }

#pragma unroll
  for (int ii = 0; ii < 2; ++ii) {
    const int i = T0 + rep * 2 + ii;
    const int j0 = jp, j1 = jp + 64;
    const float v0 = acc0[ii] * 0.125f, v1 = acc1[ii] * 0.125f;
    const bool val0 = (j0 <= i), val1 = (j1 <= i);
    float m = fmaxf(val0 ? v0 : -3.402823466e38f, val1 ? v1 : -3.402823466e38f);
#pragma unroll
    for (int s = 1; s < 64; s <<= 1) m = fmaxf(m, __shfl_xor(m, s, 64));
    const float e0 = val0 ? __expf(v0 - m) : 0.0f;
    const float e1 = val1 ? __expf(v1 - m) : 0.0f;
    float ss = e0 + e1;
#pragma unroll
    for (int s = 1; s < 64; s <<= 1) ss += __shfl_xor(ss, s, 64);
    const float rden = 1.0f / ss;
    float* orow = out + ((size_t)b * NB + i) * NC;
    orow[j0] = (j0 < i) ? e0 * rden : 0.0f;
    orow[j1] = (j1 < i) ? e1 * rden : 0.0f;
    if (jp == 0) orow[128] = 0.0f;
  }
}

// ---------------------------------------------------------------------------
extern "C" void kernel_launch(void* const* d_in, const int* in_sizes, int n_in,
                              void* d_out, int out_size, void* d_ws, size_t ws_size,
                              hipStream_t stream) {
  const float* q = (const float*)d_in[0];
  const float* k = (const float*)d_in[1];
  float* out = (float*)d_out;

  float* ws     = (float*)d_ws;
  float* qsum   = ws;                            // BH*NB*D
  float* ksum   = qsum   + (size_t)BH * NB * D;
  float* kw     = ksum   + (size_t)BH * NB * D;
  float* qfirst = kw     + (size_t)BH * NB * D;
  float* sq     = qfirst + (size_t)BH * NB * D;
  float* skp    = sq     + (size_t)BH * NB * D;  // BH*NC*D
  float* W      = skp    + (size_t)BH * NC * D;  // NB

  kA<<<dim3(NB, BH, 2), 256, 0, stream>>>(q, k, qsum, ksum, kw, qfirst, W);
  kB<<<dim3(2, BH), 256, 0, stream>>>(qsum, ksum, kw, qfirst, W, sq, skp);
  kC<<<dim3(16, BH), 256, 0, stream>>>(sq, skp, out);
}

// Round 9
// 148.420 us; speedup vs baseline: 1.0821x; 1.0088x over previous
//
#include <hip/hip_runtime.h>
#include <cstddef>

constexpr int BH = 32;    // batch*heads
constexpr int N  = 8192;  // sequence
constexpr int D  = 64;    // dim
constexpr int BK = 64;    // bucket size
constexpr int NB = 128;   // N / BK buckets
constexpr int NC = 129;   // NB + 1 (padded sk)

typedef float v4f __attribute__((ext_vector_type(4)));  // native vector for NT builtins

// ---------------------------------------------------------------------------
// Kernel A: block per (bucket j, b); loads BOTH q- and k-buckets with 8
// independent NON-TEMPORAL loads per thread (R5 structure + R8's NT win —
// single-variable test: does request depth pay on the NT read path?).
// In-wave suffix harmonic scan for tailw (no LDS phase), shuffle reduce,
// one barrier, 3 KB LDS combine.
// ---------------------------------------------------------------------------
__global__ __launch_bounds__(256) void kA(const float* __restrict__ q,
                                          const float* __restrict__ k,
                                          float* __restrict__ qsum,
                                          float* __restrict__ ksum,
                                          float* __restrict__ kw,
                                          float* __restrict__ qfirst,
                                          float* __restrict__ W) {
  const int j = blockIdx.x, b = blockIdx.y;
  const int tid  = threadIdx.x;
  const int f    = tid & 15;      // float4 column
  const int rr   = tid >> 4;      // row-group 0..15 (rows 16p + rr)
  const int w    = tid >> 6;      // wave
  const int lane = tid & 63;
  const int base = j * BK;
  const size_t ob = ((size_t)b * NB + j) * D;

  const v4f* q4 = (const v4f*)(q + ((size_t)b * N + base) * D);
  const v4f* k4 = (const v4f*)(k + ((size_t)b * N + base) * D);

  // ---- 8 independent NT loads, all issued before any consumer
  v4f vq[4], vk[4];
#pragma unroll
  for (int p = 0; p < 4; ++p) vq[p] = __builtin_nontemporal_load(&q4[(16 * p + rr) * 16 + f]);
#pragma unroll
  for (int p = 0; p < 4; ++p) vk[p] = __builtin_nontemporal_load(&k4[(16 * p + rr) * 16 + f]);

  // ---- in-wave suffix harmonic scan (overlaps loads):
  // x[lane] = sum_{u>=lane} 1/(base+u+1)
  float x = 1.0f / (float)(base + lane + 1);
#pragma unroll
  for (int s = 1; s < 64; s <<= 1) {
    const float y = __shfl_down(x, s, 64);
    if (lane + s < 64) x += y;
  }
  float tw[4];
#pragma unroll
  for (int p = 0; p < 4; ++p) tw[p] = __shfl(x, 16 * p + rr, 64);

  // ---- accumulate
  float aq[4] = {0, 0, 0, 0}, ak[4] = {0, 0, 0, 0}, aw[4] = {0, 0, 0, 0};
#pragma unroll
  for (int p = 0; p < 4; ++p) {
    aq[0] += vq[p].x; aq[1] += vq[p].y; aq[2] += vq[p].z; aq[3] += vq[p].w;
    ak[0] += vk[p].x; ak[1] += vk[p].y; ak[2] += vk[p].z; ak[3] += vk[p].w;
    aw[0] += vk[p].x * tw[p]; aw[1] += vk[p].y * tw[p];
    aw[2] += vk[p].z * tw[p]; aw[3] += vk[p].w * tw[p];
  }

  // ---- reduce over the 4 row-groups resident in this wave (lane = (rr&3)*16+f)
#pragma unroll
  for (int c = 0; c < 4; ++c) {
    aq[c] += __shfl_xor(aq[c], 16, 64); aq[c] += __shfl_xor(aq[c], 32, 64);
    ak[c] += __shfl_xor(ak[c], 16, 64); ak[c] += __shfl_xor(ak[c], 32, 64);
    aw[c] += __shfl_xor(aw[c], 16, 64); aw[c] += __shfl_xor(aw[c], 32, 64);
  }

  __shared__ float red[3][4][D];   // 3 KB
  if (lane < 16) {                 // lane == f
    ((float4*)&red[0][w][0])[f] = make_float4(aq[0], aq[1], aq[2], aq[3]);
    ((float4*)&red[1][w][0])[f] = make_float4(ak[0], ak[1], ak[2], ak[3]);
    ((float4*)&red[2][w][0])[f] = make_float4(aw[0], aw[1], aw[2], aw[3]);
  }
  if (rr == 0) {                   // rows 16p+0, p=0 -> bucket row 0 (q)
    ((float4*)(qfirst + ob))[f] = make_float4(vq[0].x, vq[0].y, vq[0].z, vq[0].w);
  }
  if (tid == 0 && b == 0) W[j] = x;  // lane 0: full-bucket harmonic
  __syncthreads();

  if (tid < 192) {
    const int arr = tid >> 6, d = tid & 63;
    const float s = red[arr][0][d] + red[arr][1][d] + red[arr][2][d] + red[arr][3][d];
    float* dst = (arr == 0) ? qsum : (arr == 1) ? ksum : kw;
    dst[ob + d] = s;
  }
}

// ---------------------------------------------------------------------------
// Kernel B: prefix scan. grid (2, BH): x=0 -> q side (sq), x=1 -> k side (skp).
// Stage the scanned array in LDS (coalesced float4), scan from LDS.
// ---------------------------------------------------------------------------
__global__ __launch_bounds__(256) void kB(const float* __restrict__ qsum,
                                          const float* __restrict__ ksum,
                                          const float* __restrict__ kw,
                                          const float* __restrict__ qfirst,
                                          const float* __restrict__ W,
                                          float* __restrict__ sq,
                                          float* __restrict__ skp) {
  const int side = blockIdx.x;
  const int b    = blockIdx.y;
  const int tid  = threadIdx.x;
  const int d    = tid & 63;
  const int jg   = tid >> 6;

  __shared__ float buf[NB * D];
  __shared__ float tot[4 * D];
  __shared__ float Wl[NB];

  const float* src = (side == 0 ? qsum : ksum) + (size_t)b * NB * D;
  {
    const float4* g4 = (const float4*)src;
    float4* l4 = (float4*)buf;
    for (int u = tid; u < NB * D / 4; u += 256) l4[u] = g4[u];
    if (side == 1 && tid < NB) Wl[tid] = W[tid];
  }
  __syncthreads();

  float t0 = 0.0f;
  for (int jj = 0; jj < 32; ++jj) t0 += buf[(jg * 32 + jj) * D + d];
  tot[jg * D + d] = t0;
  __syncthreads();

  float pre = 0.0f;
  for (int g = 0; g < jg; ++g) pre += tot[g * D + d];

  if (side == 0) {
    for (int jj = 0; jj < 32; ++jj) {
      const int j = jg * 32 + jj;
      const size_t o = ((size_t)b * NB + j) * D + d;
      sq[o] = (pre + qfirst[o]) / (float)(j * BK + 1);
      pre += buf[j * D + d];
    }
  } else {
    if (tid < D) skp[(size_t)b * NC * D + tid] = 0.0f;  // pad row 0
    for (int jj = 0; jj < 32; ++jj) {
      const int j = jg * 32 + jj;
      const size_t o = ((size_t)b * NB + j) * D + d;
      skp[((size_t)b * NC + j + 1) * D + d] = pre * Wl[j] + kw[o];
      pre += buf[j * D + d];
    }
  }
}

// ---------------------------------------------------------------------------
// Kernel C: scores+softmax. grid (16, BH): 8-row i-tile per block. Stages only
// the skp rows j <= i_max = T0+7 (XOR-swizzled) + the 8-row sq tile.
// Thread (jp, rep): cols {jp, jp+64}, rows {2rep, 2rep+1}. Col 128 never computed.
// ---------------------------------------------------------------------------
__global__ __launch_bounds__(256) void kC(const float* __restrict__ sq,
                                          const float* __restrict__ skp,
                                          float* __restrict__ out) {
  const int tile = blockIdx.x, b = blockIdx.y;
  const int tid = threadIdx.x;
  const int jp = tid & 63, rep = tid >> 6;
  const int T0 = tile * 8;
  const int rows = T0 + 8;   // skp rows needed: 0..T0+7

  __shared__ float skpS[NB * D];   // 32 KB max (only `rows` rows staged)
  __shared__ float sqs[8 * D];     // 2 KB

  {
    const float4* g4 = (const float4*)(skp + (size_t)b * NC * D);
    for (int u = tid; u < rows * 16; u += 256) {
      const int row = u >> 4, f = u & 15;
      ((float4*)skpS)[row * 16 + ((f + row) & 15)] = g4[u];
    }
    if (tid < 128)
      ((float4*)sqs)[tid] = ((const float4*)(sq + ((size_t)b * NB + T0) * D))[tid];
  }
  __syncthreads();

  float acc0[2] = {0, 0}, acc1[2] = {0, 0};
  const float4* sk4 = (const float4*)skpS;
  const float4* sq4 = (const float4*)sqs;
#pragma unroll
  for (int d4 = 0; d4 < 16; ++d4) {
    const int slot = (d4 + jp) & 15;           // same slot for jp and jp+64
    const float4 k0 = sk4[jp * 16 + slot];
    const float4 k1 = sk4[(jp + 64) * 16 + slot];
#pragma unroll
    for (int ii = 0; ii < 2; ++ii) {
      const float4 s = sq4[(rep * 2 + ii) * 16 + d4];
      acc0[ii] += s.x * k0.x + s.y * k0.y + s.z * k0.z + s.w * k0.w;
      acc1[ii] += s.x * k1.x + s.y * k1.y + s.z * k1.z + s.w * k1.w;
    }
  }

#pragma unroll
  for (int ii = 0; ii < 2; ++ii) {
    const int i = T0 + rep * 2 + ii;
    const int j0 = jp, j1 = jp + 64;
    const float v0 = acc0[ii] * 0.125f, v1 = acc1[ii] * 0.125f;
    const bool val0 = (j0 <= i), val1 = (j1 <= i);
    float m = fmaxf(val0 ? v0 : -3.402823466e38f, val1 ? v1 : -3.402823466e38f);
#pragma unroll
    for (int s = 1; s < 64; s <<= 1) m = fmaxf(m, __shfl_xor(m, s, 64));
    const float e0 = val0 ? __expf(v0 - m) : 0.0f;
    const float e1 = val1 ? __expf(v1 - m) : 0.0f;
    float ss = e0 + e1;
#pragma unroll
    for (int s = 1; s < 64; s <<= 1) ss += __shfl_xor(ss, s, 64);
    const float rden = 1.0f / ss;
    float* orow = out + ((size_t)b * NB + i) * NC;
    orow[j0] = (j0 < i) ? e0 * rden : 0.0f;
    orow[j1] = (j1 < i) ? e1 * rden : 0.0f;
    if (jp == 0) orow[128] = 0.0f;
  }
}

// ---------------------------------------------------------------------------
extern "C" void kernel_launch(void* const* d_in, const int* in_sizes, int n_in,
                              void* d_out, int out_size, void* d_ws, size_t ws_size,
                              hipStream_t stream) {
  const float* q = (const float*)d_in[0];
  const float* k = (const float*)d_in[1];
  float* out = (float*)d_out;

  float* ws     = (float*)d_ws;
  float* qsum   = ws;                            // BH*NB*D
  float* ksum   = qsum   + (size_t)BH * NB * D;
  float* kw     = ksum   + (size_t)BH * NB * D;
  float* qfirst = kw     + (size_t)BH * NB * D;
  float* sq     = qfirst + (size_t)BH * NB * D;
  float* skp    = sq     + (size_t)BH * NB * D;  // BH*NC*D
  float* W      = skp    + (size_t)BH * NC * D;  // NB

  kA<<<dim3(NB, BH), 256, 0, stream>>>(q, k, qsum, ksum, kw, qfirst, W);
  kB<<<dim3(2, BH), 256, 0, stream>>>(qsum, ksum, kw, qfirst, W, sq, skp);
  kC<<<dim3(16, BH), 256, 0, stream>>>(sq, skp, out);
}